// Round 7
// baseline (546.832 us; speedup 1.0000x reference)
//
#include <hip/hip_runtime.h>

#define H 128
#define NSRC 3

typedef _Float16 f16;
typedef _Float16 f16x2 __attribute__((ext_vector_type(2)));
typedef _Float16 f16x4 __attribute__((ext_vector_type(4)));
typedef _Float16 f16x8 __attribute__((ext_vector_type(8)));
typedef float f32x4 __attribute__((ext_vector_type(4)));

// ---------------------------------------------------------------------------
__global__ void zero_kernel(int* __restrict__ p, int n) {
    int i = blockIdx.x * blockDim.x + threadIdx.x;
    if (i < n) p[i] = 0;
}

// ---------------------------------------------------------------------------
// prep W: fp32 [384][128] -> f16 per-src [c][k] transposed, PRE-SWIZZLED
//   byte off within src = (c*256 + k*2) ^ ((c&7)<<4); src stride 32768 B
// ---------------------------------------------------------------------------
__global__ void prep_w_kernel(const float* __restrict__ W, f16* __restrict__ wbuf) {
    int g = blockIdx.x * blockDim.x + threadIdx.x;
    if (g >= NSRC * H * H) return;
    int src = g >> 14;
    int k = (g >> 7) & 127;
    int c = g & 127;
    float v = W[((size_t)src * H + k) * H + c];
    unsigned off = ((unsigned)(c * 256 + k * 2)) ^ ((unsigned)((c & 7) << 4));
    wbuf[(size_t)src * (H * H) + (off >> 1)] = (f16)v;
}

// ---------------------------------------------------------------------------
__global__ void prep_nf_kernel(const float* __restrict__ nf, f16* __restrict__ nfh, int n) {
    int i = (blockIdx.x * blockDim.x + threadIdx.x) * 4;
    if (i >= n) return;
    float4 v = *(const float4*)(nf + i);
    f16x4 h;
    h[0] = (f16)v.x; h[1] = (f16)v.y; h[2] = (f16)v.z; h[3] = (f16)v.w;
    *(f16x4*)(nfh + i) = h;
}

// ---------------------------------------------------------------------------
// Counting sort by receiver: hist -> scan -> scatter
// ---------------------------------------------------------------------------
__global__ void hist_kernel(const int* __restrict__ recv, int* __restrict__ cnt, int n_edges) {
    int e = blockIdx.x * blockDim.x + threadIdx.x;
    if (e < n_edges) atomicAdd(&cnt[recv[e]], 1);
}

__global__ void scan_kernel(const int* __restrict__ cnt, int* __restrict__ row_ptr,
                            int* __restrict__ cursor, int n) {
    __shared__ int sd[1024];
    const int t = threadIdx.x;
    const int per = (n + 1023) >> 10;
    const int st = t * per;
    const int en = min(st + per, n);
    int s = 0;
    for (int i = st; i < en; ++i) s += cnt[i];
    sd[t] = s;
    __syncthreads();
    for (int off = 1; off < 1024; off <<= 1) {
        int v = 0;
        if (t >= off) v = sd[t - off];
        __syncthreads();
        sd[t] += v;
        __syncthreads();
    }
    int run = sd[t] - s;  // exclusive prefix of this chunk
    for (int i = st; i < en; ++i) {
        row_ptr[i] = run;
        cursor[i] = run;
        run += cnt[i];
    }
    if (t == 1023) row_ptr[n] = sd[1023];
}

__global__ void scatter_kernel(const int* __restrict__ send, const int* __restrict__ recv,
                               int* __restrict__ cursor, int* __restrict__ perm,
                               int* __restrict__ ssend, int* __restrict__ srecv, int n_edges) {
    int e = blockIdx.x * blockDim.x + threadIdx.x;
    if (e < n_edges) {
        int r = recv[e];
        int pos = atomicAdd(&cursor[r], 1);
        perm[pos] = e;
        ssend[pos] = send[e];
        srecv[pos] = r;
    }
}

// ---------------------------------------------------------------------------
// Node projections (fp32 in, convert on the fly):
//   PS = f16(NF)@W1 (f16 out), PR = f16(NF)@W2 + b (fp32 out)
// ---------------------------------------------------------------------------
__global__ __launch_bounds__(256, 2)
void node_proj_kernel(const float* __restrict__ nf, const float* __restrict__ b,
                      const f16* __restrict__ wbuf, f16* __restrict__ PS,
                      float* __restrict__ PR, int n_nodes) {
    __shared__ __align__(16) f16 Wlds[2 * H * H];  // 64 KB: W1, W2
    const int t = threadIdx.x;
    {
        const int4* g = (const int4*)wbuf;
        int4* d = (int4*)Wlds;
#pragma unroll
        for (int i = 0; i < 16; ++i) d[i * 256 + t] = g[i * 256 + t];
    }
    __syncthreads();

    const int lane = t & 63;
    const int wid = t >> 6;
    const int l15 = lane & 15;
    const int lg = lane >> 4;
    const int r0 = (blockIdx.x * 4 + wid) * 64;
    if (r0 >= n_nodes) return;

#pragma unroll
    for (int src = 0; src < 2; ++src) {
        f32x4 acc[4][8];
#pragma unroll
        for (int rf = 0; rf < 4; ++rf)
#pragma unroll
            for (int cf = 0; cf < 8; ++cf) acc[rf][cf] = (f32x4){0.f, 0.f, 0.f, 0.f};

#pragma unroll
        for (int ks = 0; ks < 4; ++ks) {
            f16x8 a[4];
#pragma unroll
            for (int rf = 0; rf < 4; ++rf) {
                int row = r0 + rf * 16 + l15;
                if (row >= n_nodes) row = n_nodes - 1;
                const float* p = nf + (size_t)row * H + ks * 32 + lg * 8;
                float4 v0 = *(const float4*)p;
                float4 v1 = *(const float4*)(p + 4);
                f16x8 h;
                h[0] = (f16)v0.x; h[1] = (f16)v0.y; h[2] = (f16)v0.z; h[3] = (f16)v0.w;
                h[4] = (f16)v1.x; h[5] = (f16)v1.y; h[6] = (f16)v1.z; h[7] = (f16)v1.w;
                a[rf] = h;
            }
#pragma unroll
            for (int cf = 0; cf < 8; ++cf) {
                const int c = cf * 16 + l15;
                unsigned off = ((unsigned)(src * 32768 + c * 256 + (ks * 32 + lg * 8) * 2))
                               ^ ((unsigned)((c & 7) << 4));
                f16x8 bf = *(const f16x8*)((const char*)Wlds + off);
#pragma unroll
                for (int rf = 0; rf < 4; ++rf)
                    acc[rf][cf] = __builtin_amdgcn_mfma_f32_16x16x32_f16(
                        a[rf], bf, acc[rf][cf], 0, 0, 0);
            }
        }

#pragma unroll
        for (int rf = 0; rf < 4; ++rf) {
#pragma unroll
            for (int q = 0; q < 4; ++q) {
                const int row = r0 + rf * 16 + lg * 4 + q;
                if (row < n_nodes) {
#pragma unroll
                    for (int cf = 0; cf < 8; ++cf) {
                        const int col = cf * 16 + l15;
                        if (src == 0)
                            PS[(size_t)row * H + col] = (f16)acc[rf][cf][q];
                        else
                            PR[(size_t)row * H + col] = acc[rf][cf][q] + b[col];
                    }
                }
            }
        }
    }
}

// ---------------------------------------------------------------------------
// FUSED: per 64-sorted-edge tile: gather EF[perm] -> MFMA vs W3 (regs) ->
// raw messages to LDS -> segmented reduce (add PS[s]+PR[r], relu, sum) ->
// one atomicAdd per lane per receiver-segment into AGG.
// Waves split cols for MFMA (wave wid owns cols [wid*32, wid*32+32));
// waves split rows for reduce (wave wid owns rows [wid*16, wid*16+16)).
// 2 barriers per tile; LDS 32 KB.
// ---------------------------------------------------------------------------
__global__ __launch_bounds__(256, 2)
void fused_msg_kernel(const float* __restrict__ ef, const int* __restrict__ perm,
                      const int* __restrict__ ssend, const int* __restrict__ srecv,
                      const f16* __restrict__ wbuf, const f16* __restrict__ PS,
                      const float* __restrict__ PR, float* __restrict__ AGG,
                      int n_edges) {
    __shared__ __align__(16) f16 Alds[64 * H];  // 16 KB
    __shared__ __align__(16) f16 MSG[64 * H];   // 16 KB

    const int t = threadIdx.x;
    const int lane = t & 63;
    const int wid = t >> 6;  // 0..3
    const int l15 = lane & 15;
    const int lg = lane >> 4;
    const int c2 = lane * 2;

    // B fragments (W3, this wave's 32 cols, full K) in registers — loaded once
    const char* w3 = (const char*)(wbuf + (size_t)2 * H * H);
    f16x8 breg[2][4];
#pragma unroll
    for (int cf = 0; cf < 2; ++cf)
#pragma unroll
        for (int ks = 0; ks < 4; ++ks) {
            const int c = wid * 32 + cf * 16 + l15;
            const int kb = ks * 32 + lg * 8;
            unsigned off = ((unsigned)(c * 256 + kb * 2)) ^ ((unsigned)((c & 7) << 4));
            breg[cf][ks] = *(const f16x8*)(w3 + off);
        }

    const int srow = t >> 2;        // staging: row 0..63
    const int kp = (t & 3) * 32;    // staging: k-range
    const int ntiles = (n_edges + 63) >> 6;

    for (int tile = blockIdx.x; tile < ntiles; tile += gridDim.x) {
        const int e0 = tile * 64;

        // ---- stage A: gather EF[perm[e]], cvt f16, swizzled LDS write ----
        {
            int e = e0 + srow;
            if (e >= n_edges) e = n_edges - 1;
            const float* p = ef + (size_t)perm[e] * H + kp;
#pragma unroll
            for (int i = 0; i < 4; ++i) {
                float4 v0 = *(const float4*)(p + i * 8);
                float4 v1 = *(const float4*)(p + i * 8 + 4);
                f16x8 h;
                h[0] = (f16)v0.x; h[1] = (f16)v0.y; h[2] = (f16)v0.z; h[3] = (f16)v0.w;
                h[4] = (f16)v1.x; h[5] = (f16)v1.y; h[6] = (f16)v1.z; h[7] = (f16)v1.w;
                unsigned off = ((unsigned)(srow * 256 + (kp + i * 8) * 2))
                               ^ ((unsigned)((srow & 7) << 4));
                *(f16x8*)((char*)Alds + off) = h;
            }
        }
        __syncthreads();  // A ready; also: all waves' prev-tile reduce done

        // ---- MFMA: all 64 rows x this wave's 32 cols ----
        f32x4 acc[4][2];
#pragma unroll
        for (int rf = 0; rf < 4; ++rf) {
            acc[rf][0] = (f32x4){0.f, 0.f, 0.f, 0.f};
            acc[rf][1] = (f32x4){0.f, 0.f, 0.f, 0.f};
        }
#pragma unroll
        for (int ks = 0; ks < 4; ++ks) {
            f16x8 af[4];
#pragma unroll
            for (int rf = 0; rf < 4; ++rf) {
                const int row = rf * 16 + l15;
                unsigned off = ((unsigned)(row * 256 + (ks * 32 + lg * 8) * 2))
                               ^ ((unsigned)((row & 7) << 4));
                af[rf] = *(const f16x8*)((const char*)Alds + off);
            }
#pragma unroll
            for (int rf = 0; rf < 4; ++rf) {
                acc[rf][0] = __builtin_amdgcn_mfma_f32_16x16x32_f16(af[rf], breg[0][ks], acc[rf][0], 0, 0, 0);
                acc[rf][1] = __builtin_amdgcn_mfma_f32_16x16x32_f16(af[rf], breg[1][ks], acc[rf][1], 0, 0, 0);
            }
        }

        // ---- raw messages -> MSG (f16). C/D: col=lane&15, row=(lane>>4)*4+q ----
#pragma unroll
        for (int rf = 0; rf < 4; ++rf)
#pragma unroll
            for (int cf = 0; cf < 2; ++cf)
#pragma unroll
                for (int q = 0; q < 4; ++q) {
                    const int row = rf * 16 + lg * 4 + q;
                    const int col = wid * 32 + cf * 16 + l15;
                    MSG[row * H + col] = (f16)acc[rf][cf][q];
                }
        __syncthreads();  // MSG complete across all waves

        // ---- segmented reduce over this wave's 16 sorted rows ----
        float ax = 0.f, ay = 0.f;
        int cur = -1;
        float prx = 0.f, pry = 0.f;
#pragma unroll 1
        for (int rr = 0; rr < 16; ++rr) {
            const int e = e0 + wid * 16 + rr;
            if (e >= n_edges) break;
            const int r = srecv[e];
            if (r != cur) {
                if (cur >= 0) {
                    atomicAdd(&AGG[(size_t)cur * H + c2], ax);
                    atomicAdd(&AGG[(size_t)cur * H + c2 + 1], ay);
                }
                ax = 0.f; ay = 0.f; cur = r;
                float2 prv = *(const float2*)&PR[(size_t)r * H + c2];
                prx = prv.x; pry = prv.y;
            }
            const int s = ssend[e];
            f16x2 m = *(const f16x2*)&MSG[(wid * 16 + rr) * H + c2];
            f16x2 ps = *(const f16x2*)&PS[(size_t)s * H + c2];
            ax += fmaxf((float)ps[0] + prx + (float)m[0], 0.f);
            ay += fmaxf((float)ps[1] + pry + (float)m[1], 0.f);
        }
        if (cur >= 0) {
            atomicAdd(&AGG[(size_t)cur * H + c2], ax);
            atomicAdd(&AGG[(size_t)cur * H + c2 + 1], ay);
        }
    }
}

// ---------------------------------------------------------------------------
// LayerNorm(nf + AGG) -> out
// ---------------------------------------------------------------------------
__global__ __launch_bounds__(256, 4)
void ln_agg_kernel(const float* __restrict__ nf, const float* __restrict__ AGG,
                   const float* __restrict__ lnw, const float* __restrict__ lnb,
                   float* __restrict__ out, int n_nodes) {
    const int wv = threadIdx.x >> 6;
    const int lane = threadIdx.x & 63;
    const int row = blockIdx.x * (blockDim.x >> 6) + wv;
    if (row >= n_nodes) return;
    float2 a = ((const float2*)(nf + (size_t)row * H))[lane];
    float2 g = ((const float2*)(AGG + (size_t)row * H))[lane];
    float vx = a.x + g.x, vy = a.y + g.y;

    float s = vx + vy;
#pragma unroll
    for (int m = 32; m; m >>= 1) s += __shfl_xor(s, m, 64);
    float mu = s * (1.f / H);
    float dx = vx - mu, dy = vy - mu;
    float q = dx * dx + dy * dy;
#pragma unroll
    for (int m = 32; m; m >>= 1) q += __shfl_xor(q, m, 64);
    float rs = rsqrtf(q * (1.f / H) + 1e-5f);

    float2 w2 = ((const float2*)lnw)[lane];
    float2 b2 = ((const float2*)lnb)[lane];
    float2 o;
    o.x = dx * rs * w2.x + b2.x;
    o.y = dy * rs * w2.y + b2.y;
    ((float2*)(out + (size_t)row * H))[lane] = o;
}

// ---------------------------------------------------------------------------
// Fallback path (R4): barrier-free fused GEMM with atomics + separate LN
// ---------------------------------------------------------------------------
__global__ __launch_bounds__(512, 2)
void fused_edge_kernel(const f16* __restrict__ nfh, const int* __restrict__ senders,
                       const int* __restrict__ receivers, const float* __restrict__ ef,
                       const float* __restrict__ b, const f16* __restrict__ wbuf,
                       float* __restrict__ out, int n_edges) {
    __shared__ __align__(16) f16 Wlds[NSRC * H * H];  // 96 KB
    const int t = threadIdx.x;
    {
        const int4* g = (const int4*)wbuf;
        int4* d = (int4*)Wlds;
#pragma unroll
        for (int i = 0; i < 12; ++i) d[i * 512 + t] = g[i * 512 + t];
    }
    __syncthreads();

    const int lane = t & 63;
    const int wid = t >> 6;
    const int l15 = lane & 15;
    const int lg = lane >> 4;

    float bias[8];
#pragma unroll
    for (int cf = 0; cf < 8; ++cf) bias[cf] = b[cf * 16 + l15];

    const int ntiles = (n_edges + 63) >> 6;
    const int nworkers = gridDim.x * 8;

    for (int tile = blockIdx.x * 8 + wid; tile < ntiles; tile += nworkers) {
        const int e0 = tile * 64;
        int sid[4], rid[4];
#pragma unroll
        for (int rf = 0; rf < 4; ++rf) {
            int e = e0 + rf * 16 + l15;
            if (e >= n_edges) e = n_edges - 1;
            sid[rf] = senders[e];
            rid[rf] = receivers[e];
        }
        f32x4 acc[4][8];
#pragma unroll
        for (int rf = 0; rf < 4; ++rf)
#pragma unroll
            for (int cf = 0; cf < 8; ++cf) acc[rf][cf] = (f32x4){0.f, 0.f, 0.f, 0.f};

#pragma unroll
        for (int src = 0; src < 2; ++src) {
#pragma unroll
            for (int ks = 0; ks < 4; ++ks) {
                f16x8 a[4];
#pragma unroll
                for (int rf = 0; rf < 4; ++rf) {
                    const int row = (src == 0) ? sid[rf] : rid[rf];
                    a[rf] = *(const f16x8*)(nfh + (size_t)row * H + ks * 32 + lg * 8);
                }
#pragma unroll
                for (int cf = 0; cf < 8; ++cf) {
                    const int c = cf * 16 + l15;
                    unsigned off = ((unsigned)(src * 32768 + c * 256 + (ks * 32 + lg * 8) * 2))
                                   ^ ((unsigned)((c & 7) << 4));
                    f16x8 bf = *(const f16x8*)((const char*)Wlds + off);
#pragma unroll
                    for (int rf = 0; rf < 4; ++rf)
                        acc[rf][cf] = __builtin_amdgcn_mfma_f32_16x16x32_f16(
                            a[rf], bf, acc[rf][cf], 0, 0, 0);
                }
            }
        }
#pragma unroll
        for (int ks = 0; ks < 4; ++ks) {
            f16x8 a[4];
#pragma unroll
            for (int rf = 0; rf < 4; ++rf) {
                int e = e0 + rf * 16 + l15;
                if (e >= n_edges) e = n_edges - 1;
                const float* p = ef + (size_t)e * H + ks * 32 + lg * 8;
                float4 v0 = *(const float4*)p;
                float4 v1 = *(const float4*)(p + 4);
                f16x8 h;
                h[0] = (f16)v0.x; h[1] = (f16)v0.y; h[2] = (f16)v0.z; h[3] = (f16)v0.w;
                h[4] = (f16)v1.x; h[5] = (f16)v1.y; h[6] = (f16)v1.z; h[7] = (f16)v1.w;
                a[rf] = h;
            }
#pragma unroll
            for (int cf = 0; cf < 8; ++cf) {
                const int c = cf * 16 + l15;
                unsigned off = ((unsigned)(2 * 32768 + c * 256 + (ks * 32 + lg * 8) * 2))
                               ^ ((unsigned)((c & 7) << 4));
                f16x8 bf = *(const f16x8*)((const char*)Wlds + off);
#pragma unroll
                for (int rf = 0; rf < 4; ++rf)
                    acc[rf][cf] = __builtin_amdgcn_mfma_f32_16x16x32_f16(
                        a[rf], bf, acc[rf][cf], 0, 0, 0);
            }
        }
#pragma unroll
        for (int rf = 0; rf < 4; ++rf) {
#pragma unroll
            for (int q = 0; q < 4; ++q) {
                const int e = e0 + rf * 16 + lg * 4 + q;
                if (e < n_edges) {
                    const int r = receivers[e];
                    float* dst = out + (size_t)r * H;
#pragma unroll
                    for (int cf = 0; cf < 8; ++cf) {
                        float m = fmaxf(acc[rf][cf][q] + bias[cf], 0.f);
                        atomicAdd(dst + cf * 16 + l15, m);
                    }
                }
            }
        }
    }
}

__global__ __launch_bounds__(256, 4)
void ln_kernel(const float* __restrict__ nf, const float* __restrict__ lnw,
               const float* __restrict__ lnb, float* __restrict__ out, int n_nodes) {
    const int wv = threadIdx.x >> 6;
    const int lane = threadIdx.x & 63;
    const int row = blockIdx.x * (blockDim.x >> 6) + wv;
    if (row >= n_nodes) return;
    float2 a = ((const float2*)(nf + (size_t)row * H))[lane];
    float2 g = ((float2*)(out + (size_t)row * H))[lane];
    float vx = a.x + g.x, vy = a.y + g.y;
    float s = vx + vy;
#pragma unroll
    for (int m = 32; m; m >>= 1) s += __shfl_xor(s, m, 64);
    float mu = s * (1.f / H);
    float dx = vx - mu, dy = vy - mu;
    float q = dx * dx + dy * dy;
#pragma unroll
    for (int m = 32; m; m >>= 1) q += __shfl_xor(q, m, 64);
    float rs = rsqrtf(q * (1.f / H) + 1e-5f);
    float2 w2 = ((const float2*)lnw)[lane];
    float2 b2 = ((const float2*)lnb)[lane];
    float2 o;
    o.x = dx * rs * w2.x + b2.x;
    o.y = dy * rs * w2.y + b2.y;
    ((float2*)(out + (size_t)row * H))[lane] = o;
}

__global__ void naive_edge_kernel(const float* __restrict__ nf, const int* __restrict__ s,
                                  const int* __restrict__ r, const float* __restrict__ ef,
                                  const float* __restrict__ W, const float* __restrict__ b,
                                  float* __restrict__ out, int n_edges) {
    int e = blockIdx.x * 2 + (threadIdx.x >> 7);
    int c = threadIdx.x & 127;
    if (e >= n_edges) return;
    int se = s[e], re = r[e];
    float acc = b[c];
    for (int k = 0; k < H; ++k) {
        acc += nf[(size_t)se * H + k] * W[(size_t)k * H + c];
        acc += nf[(size_t)re * H + k] * W[(size_t)(H + k) * H + c];
        acc += ef[(size_t)e * H + k] * W[(size_t)(2 * H + k) * H + c];
    }
    atomicAdd(&out[(size_t)re * H + c], fmaxf(acc, 0.f));
}

// ---------------------------------------------------------------------------
extern "C" void kernel_launch(void* const* d_in, const int* in_sizes, int n_in,
                              void* d_out, int out_size, void* d_ws, size_t ws_size,
                              hipStream_t stream) {
    const float* nf        = (const float*)d_in[0];
    const int*   senders   = (const int*)d_in[1];
    const int*   receivers = (const int*)d_in[2];
    const float* ef        = (const float*)d_in[3];
    const float* W         = (const float*)d_in[4];
    const float* b         = (const float*)d_in[5];
    const float* lnw       = (const float*)d_in[6];
    const float* lnb       = (const float*)d_in[7];
    float* out = (float*)d_out;

    const int n_nodes = in_sizes[0] / H;  // 50000
    const int n_edges = in_sizes[1];      // 800000
    const int nfelem = n_nodes * H;

    // ws carve-out (256B aligned)
    size_t o = 0;
    auto carve = [&](size_t bytes) { size_t r = o; o += (bytes + 255) & ~(size_t)255; return r; };
    const size_t o_wbuf   = carve((size_t)NSRC * H * H * sizeof(f16));   // 96 KB
    const size_t o_nfh    = carve((size_t)nfelem * sizeof(f16));         // 12.8 MB (fallback only)
    const size_t o_cnt    = carve((size_t)n_nodes * 4);
    const size_t o_rowptr = carve((size_t)(n_nodes + 1) * 4);
    const size_t o_cursor = carve((size_t)n_nodes * 4);
    const size_t o_perm   = carve((size_t)n_edges * 4);
    const size_t o_ssend  = carve((size_t)n_edges * 4);
    const size_t o_srecv  = carve((size_t)n_edges * 4);
    const size_t o_ps     = carve((size_t)nfelem * sizeof(f16));         // 12.8 MB
    const size_t o_pr     = carve((size_t)nfelem * sizeof(float));       // 25.6 MB
    const size_t o_agg    = carve((size_t)nfelem * sizeof(float));       // 25.6 MB
    const size_t need_full = o;

    char* ws = (char*)d_ws;
    f16* wbuf = (f16*)(ws + o_wbuf);
    f16* nfh  = (f16*)(ws + o_nfh);

    if (ws_size >= need_full) {
        int* cnt    = (int*)(ws + o_cnt);
        int* rowptr = (int*)(ws + o_rowptr);
        int* cursor = (int*)(ws + o_cursor);
        int* perm   = (int*)(ws + o_perm);
        int* ssend  = (int*)(ws + o_ssend);
        int* srecv  = (int*)(ws + o_srecv);
        f16* PS     = (f16*)(ws + o_ps);
        float* PR   = (float*)(ws + o_pr);
        float* AGG  = (float*)(ws + o_agg);

        zero_kernel<<<(n_nodes + 255) / 256, 256, 0, stream>>>(cnt, n_nodes);
        zero_kernel<<<(nfelem + 255) / 256, 256, 0, stream>>>((int*)AGG, nfelem);
        prep_w_kernel<<<(NSRC * H * H + 255) / 256, 256, 0, stream>>>(W, wbuf);
        hist_kernel<<<(n_edges + 255) / 256, 256, 0, stream>>>(receivers, cnt, n_edges);
        scan_kernel<<<1, 1024, 0, stream>>>(cnt, rowptr, cursor, n_nodes);
        scatter_kernel<<<(n_edges + 255) / 256, 256, 0, stream>>>(
            senders, receivers, cursor, perm, ssend, srecv, n_edges);

        const int ntile_n = (n_nodes + 63) / 64;
        node_proj_kernel<<<(ntile_n + 3) / 4, 256, 0, stream>>>(nf, b, wbuf, PS, PR, n_nodes);
        fused_msg_kernel<<<2048, 256, 0, stream>>>(ef, perm, ssend, srecv, wbuf, PS, PR,
                                                   AGG, n_edges);
        ln_agg_kernel<<<(n_nodes + 3) / 4, 256, 0, stream>>>(nf, AGG, lnw, lnb, out, n_nodes);
    } else if (ws_size >= o_cnt) {  // enough for wbuf + nfh: R4 fallback
        hipMemsetAsync(d_out, 0, (size_t)nfelem * sizeof(float), stream);
        prep_w_kernel<<<(NSRC * H * H + 255) / 256, 256, 0, stream>>>(W, wbuf);
        prep_nf_kernel<<<(nfelem / 4 + 255) / 256, 256, 0, stream>>>(nf, nfh, nfelem);
        fused_edge_kernel<<<512, 512, 0, stream>>>(nfh, senders, receivers, ef, b,
                                                   wbuf, out, n_edges);
        ln_kernel<<<(n_nodes + 3) / 4, 256, 0, stream>>>(nf, lnw, lnb, out, n_nodes);
    } else {
        hipMemsetAsync(d_out, 0, (size_t)nfelem * sizeof(float), stream);
        naive_edge_kernel<<<(n_edges + 1) / 2, 256, 0, stream>>>(
            nf, senders, receivers, ef, W, b, out, n_edges);
        ln_kernel<<<(n_nodes + 3) / 4, 256, 0, stream>>>(nf, lnw, lnb, out, n_nodes);
    }
}